// Round 4
// baseline (500.501 us; speedup 1.0000x reference)
//
#include <hip/hip_runtime.h>

#define N 8192
#define D 128

typedef __attribute__((ext_vector_type(8))) short bf16x8;
typedef __attribute__((ext_vector_type(4))) float f32x4;

__device__ __forceinline__ unsigned short f32_to_bf16_rne(float f) {
  unsigned int u = __float_as_uint(f);
  unsigned int r = (u + 0x7FFFu + ((u >> 16) & 1u)) >> 16;
  return (unsigned short)r;
}
__device__ __forceinline__ float bf16_to_f32(unsigned short h) {
  return __uint_as_float(((unsigned int)h) << 16);
}

// Kernel A: L2-normalize pred/neg; emit phi/plo (bf16 hi/lo split of normalized
// pred), sq[i]=sum(p^2) fp32, nd[i]=safe_sqrt(sum((p-n)^2)). One wave per row.
__global__ __launch_bounds__(256) void norm_kernel(
    const float* __restrict__ pred, const float* __restrict__ neg,
    unsigned short* __restrict__ phi, unsigned short* __restrict__ plo,
    float* __restrict__ sq, float* __restrict__ nd) {
  int wv = threadIdx.x >> 6;
  int lane = threadIdx.x & 63;
  int row = blockIdx.x * 4 + wv;
  float2 x = ((const float2*)(pred + (size_t)row * D))[lane];
  float2 y = ((const float2*)(neg + (size_t)row * D))[lane];
  float sx = x.x * x.x + x.y * x.y;
  float sy = y.x * y.x + y.y * y.y;
#pragma unroll
  for (int off = 32; off; off >>= 1) {
    sx += __shfl_xor(sx, off);
    sy += __shfl_xor(sy, off);
  }
  float invx = 1.0f / fmaxf(sqrtf(sx), 1e-12f);
  float invy = 1.0f / fmaxf(sqrtf(sy), 1e-12f);
  float2 px = make_float2(x.x * invx, x.y * invx);
  float2 pn = make_float2(y.x * invy, y.y * invy);

  unsigned short h0 = f32_to_bf16_rne(px.x), h1 = f32_to_bf16_rne(px.y);
  unsigned short l0 = f32_to_bf16_rne(px.x - bf16_to_f32(h0));
  unsigned short l1 = f32_to_bf16_rne(px.y - bf16_to_f32(h1));
  ushort2 hv; hv.x = h0; hv.y = h1;
  ushort2 lv; lv.x = l0; lv.y = l1;
  ((ushort2*)(phi + (size_t)row * D))[lane] = hv;
  ((ushort2*)(plo + (size_t)row * D))[lane] = lv;

  float sp = px.x * px.x + px.y * px.y;
  float dx = px.x - pn.x, dy = px.y - pn.y;
  float sd = dx * dx + dy * dy;
#pragma unroll
  for (int off = 32; off; off >>= 1) {
    sp += __shfl_xor(sp, off);
    sd += __shfl_xor(sd, off);
  }
  if (lane == 0) {
    sq[row] = sp;
    nd[row] = sd > 0.0f ? sqrtf(sd) : 0.0f;
  }
}

// Kernel B: 128x128 tile per block; 4 waves in 2x2, each wave 64x64 output via
// 4x4 fragments of mfma_f32_16x16x32_bf16 with hi/lo 3-way split. No mask LDS:
// mask read once per element via nontemporal loads in the epilogue. Per-wave
// row partials written to a per-(jb,wj) slot, coalesced via a 2 KB LDS shuffle.
__global__ __launch_bounds__(256, 3) void pair_kernel(
    const unsigned short* __restrict__ phi, const unsigned short* __restrict__ plo,
    const float* __restrict__ sq, const float* __restrict__ mask,
    float* __restrict__ ppos, float* __restrict__ pcnt) {
  __shared__ float cbuf[4][64][2];   // [wave][row-in-64][pos,cnt]

  const int bid = blockIdx.x;
  const int swz = (bid & 7) * 512 + (bid >> 3);  // XCD swizzle, bijective (4096%8==0)
  const int ib = swz >> 6, jb = swz & 63;
  const int i0 = ib * 128, j0 = jb * 128;

  const int t = threadIdx.x;
  const int wv = t >> 6, lane = t & 63;
  const int wi = wv >> 1, wj = wv & 1;
  const int lr = lane & 15, lk = lane >> 4;

  const int arow = i0 + wi * 64 + lr;  // + fi*16
  const int brow = j0 + wj * 64 + lr;  // + fj*16

  f32x4 acc[4][4];
#pragma unroll
  for (int a = 0; a < 4; ++a)
#pragma unroll
    for (int b = 0; b < 4; ++b) acc[a][b] = (f32x4){0.f, 0.f, 0.f, 0.f};

#pragma unroll
  for (int kc = 0; kc < 4; ++kc) {
    const int kb = kc * 32 + lk * 8;
    bf16x8 ah[4], al[4], bh[4], bl[4];
#pragma unroll
    for (int f = 0; f < 4; ++f) {
      ah[f] = *(const bf16x8*)(phi + (size_t)(arow + f * 16) * D + kb);
      al[f] = *(const bf16x8*)(plo + (size_t)(arow + f * 16) * D + kb);
      bh[f] = *(const bf16x8*)(phi + (size_t)(brow + f * 16) * D + kb);
      bl[f] = *(const bf16x8*)(plo + (size_t)(brow + f * 16) * D + kb);
    }
#pragma unroll
    for (int fi = 0; fi < 4; ++fi)
#pragma unroll
      for (int fj = 0; fj < 4; ++fj) {
        acc[fi][fj] = __builtin_amdgcn_mfma_f32_16x16x32_bf16(ah[fi], bh[fj], acc[fi][fj], 0, 0, 0);
        acc[fi][fj] = __builtin_amdgcn_mfma_f32_16x16x32_bf16(ah[fi], bl[fj], acc[fi][fj], 0, 0, 0);
        acc[fi][fj] = __builtin_amdgcn_mfma_f32_16x16x32_bf16(al[fi], bh[fj], acc[fi][fj], 0, 0, 0);
      }
  }

  // Epilogue: d2 -> safe_sqrt -> mask-weighted per-row partials.
  float sqj[4];
#pragma unroll
  for (int fj = 0; fj < 4; ++fj) sqj[fj] = sq[brow + fj * 16];

  const int jcol = j0 + wj * 64 + lr;
  float pp[4][4], cc[4][4];
#pragma unroll
  for (int a = 0; a < 4; ++a)
#pragma unroll
    for (int r = 0; r < 4; ++r) { pp[a][r] = 0.f; cc[a][r] = 0.f; }

#pragma unroll
  for (int fi = 0; fi < 4; ++fi) {
    const int r4 = i0 + wi * 64 + fi * 16 + lk * 4;
#pragma unroll
    for (int r = 0; r < 4; ++r) {
      const float sqi = sq[r4 + r];
      const float* mrow = mask + (size_t)(r4 + r) * N + jcol;
#pragma unroll
      for (int fj = 0; fj < 4; ++fj) {
        float m = __builtin_nontemporal_load(mrow + fj * 16);
        float g = acc[fi][fj][r];
        float d2 = sqi + sqj[fj] - 2.0f * g;
        float dist = d2 > 0.0f ? sqrtf(d2) : 0.0f;
        pp[fi][r] = fmaf(dist, m, pp[fi][r]);
        cc[fi][r] += m;
      }
    }
  }

  // reduce across the 16 lanes (lr) sharing each row
#pragma unroll
  for (int fi = 0; fi < 4; ++fi)
#pragma unroll
    for (int r = 0; r < 4; ++r) {
#pragma unroll
      for (int off = 1; off < 16; off <<= 1) {
        pp[fi][r] += __shfl_xor(pp[fi][r], off);
        cc[fi][r] += __shfl_xor(cc[fi][r], off);
      }
    }
  if (lr == 0) {
#pragma unroll
    for (int fi = 0; fi < 4; ++fi)
#pragma unroll
      for (int r = 0; r < 4; ++r) {
        cbuf[wv][fi * 16 + lk * 4 + r][0] = pp[fi][r];
        cbuf[wv][fi * 16 + lk * 4 + r][1] = cc[fi][r];
      }
  }
  __syncthreads();
  // coalesced per-slot writes: slot = jb*2 + wj, 64 contiguous rows per wave
  {
    const size_t slotbase = (size_t)(jb * 2 + wj) * N + i0 + wi * 64;
    ppos[slotbase + lane] = cbuf[wv][lane][0];
    pcnt[slotbase + lane] = cbuf[wv][lane][1];
  }
}

// Kernel C1: per-row totals over 128 slots -> (pos_avg - nd), block-sum in double.
__global__ __launch_bounds__(256) void reduce1(
    const float* __restrict__ ppos, const float* __restrict__ pcnt,
    const float* __restrict__ nd, double* __restrict__ bsum) {
  const int t = threadIdx.x;
  const int row = blockIdx.x * 256 + t;
  float ps = 0.f, cs = 0.f;
  for (int s = 0; s < 128; ++s) {
    ps += __builtin_nontemporal_load(ppos + (size_t)s * N + row);
    cs += __builtin_nontemporal_load(pcnt + (size_t)s * N + row);
  }
  double v = (double)(ps / fmaxf(cs, 1.0f)) - (double)nd[row];
  __shared__ double sd[256];
  sd[t] = v;
  __syncthreads();
  for (int s2 = 128; s2 > 0; s2 >>= 1) {
    if (t < s2) sd[t] += sd[t + s2];
    __syncthreads();
  }
  if (t == 0) bsum[blockIdx.x] = sd[0];
}

// Kernel C2: sum 32 block partials, divide by N.
__global__ void reduce2(const double* __restrict__ bsum, float* __restrict__ out) {
  int lane = threadIdx.x;
  double v = (lane < 32) ? bsum[lane] : 0.0;
#pragma unroll
  for (int off = 32; off; off >>= 1) v += __shfl_down(v, off);
  if (lane == 0) out[0] = (float)(v / (double)N);
}

extern "C" void kernel_launch(void* const* d_in, const int* in_sizes, int n_in,
                              void* d_out, int out_size, void* d_ws, size_t ws_size,
                              hipStream_t stream) {
  const float* pred = (const float*)d_in[0];
  const float* mask = (const float*)d_in[1];
  const float* neg  = (const float*)d_in[2];
  float* out = (float*)d_out;

  char* ws = (char*)d_ws;
  unsigned short* phi = (unsigned short*)ws;  ws += (size_t)N * D * 2;   // 2 MB
  unsigned short* plo = (unsigned short*)ws;  ws += (size_t)N * D * 2;   // 2 MB
  float* sq  = (float*)ws;                    ws += (size_t)N * 4;
  float* nd  = (float*)ws;                    ws += (size_t)N * 4;
  float* ppos = (float*)ws;                   ws += (size_t)128 * N * 4; // 4 MB
  float* pcnt = (float*)ws;                   ws += (size_t)128 * N * 4; // 4 MB
  double* bsum = (double*)ws;                 ws += 32 * 8;

  norm_kernel<<<N / 4, 256, 0, stream>>>(pred, neg, phi, plo, sq, nd);
  pair_kernel<<<(N / 128) * (N / 128), 256, 0, stream>>>(phi, plo, sq, mask, ppos, pcnt);
  reduce1<<<N / 256, 256, 0, stream>>>(ppos, pcnt, nd, bsum);
  reduce2<<<1, 64, 0, stream>>>(bsum, out);
}

// Round 8
// 486.520 us; speedup vs baseline: 1.0287x; 1.0287x over previous
//
#include <hip/hip_runtime.h>

#define N 8192
#define D 128

typedef __attribute__((ext_vector_type(8))) short bf16x8;
typedef __attribute__((ext_vector_type(4))) float f32x4;

__device__ __forceinline__ unsigned short f32_to_bf16_rne(float f) {
  unsigned int u = __float_as_uint(f);
  unsigned int r = (u + 0x7FFFu + ((u >> 16) & 1u)) >> 16;
  return (unsigned short)r;
}
__device__ __forceinline__ float bf16_to_f32(unsigned short h) {
  return __uint_as_float(((unsigned int)h) << 16);
}

// Kernel A: L2-normalize pred/neg; emit phi/plo (bf16 hi/lo split of normalized
// pred), sq[i]=sum(p^2) fp32, nd[i]=safe_sqrt(sum((p-n)^2)). One wave per row.
__global__ __launch_bounds__(256) void norm_kernel(
    const float* __restrict__ pred, const float* __restrict__ neg,
    unsigned short* __restrict__ phi, unsigned short* __restrict__ plo,
    float* __restrict__ sq, float* __restrict__ nd) {
  int wv = threadIdx.x >> 6;
  int lane = threadIdx.x & 63;
  int row = blockIdx.x * 4 + wv;
  float2 x = ((const float2*)(pred + (size_t)row * D))[lane];
  float2 y = ((const float2*)(neg + (size_t)row * D))[lane];
  float sx = x.x * x.x + x.y * x.y;
  float sy = y.x * y.x + y.y * y.y;
#pragma unroll
  for (int off = 32; off; off >>= 1) {
    sx += __shfl_xor(sx, off);
    sy += __shfl_xor(sy, off);
  }
  float invx = 1.0f / fmaxf(sqrtf(sx), 1e-12f);
  float invy = 1.0f / fmaxf(sqrtf(sy), 1e-12f);
  float2 px = make_float2(x.x * invx, x.y * invx);
  float2 pn = make_float2(y.x * invy, y.y * invy);

  unsigned short h0 = f32_to_bf16_rne(px.x), h1 = f32_to_bf16_rne(px.y);
  unsigned short l0 = f32_to_bf16_rne(px.x - bf16_to_f32(h0));
  unsigned short l1 = f32_to_bf16_rne(px.y - bf16_to_f32(h1));
  ushort2 hv; hv.x = h0; hv.y = h1;
  ushort2 lv; lv.x = l0; lv.y = l1;
  ((ushort2*)(phi + (size_t)row * D))[lane] = hv;
  ((ushort2*)(plo + (size_t)row * D))[lane] = lv;

  float sp = px.x * px.x + px.y * px.y;
  float dx = px.x - pn.x, dy = px.y - pn.y;
  float sd = dx * dx + dy * dy;
#pragma unroll
  for (int off = 32; off; off >>= 1) {
    sp += __shfl_xor(sp, off);
    sd += __shfl_xor(sd, off);
  }
  if (lane == 0) {
    sq[row] = sp;
    nd[row] = sd > 0.0f ? sqrtf(sd) : 0.0f;
  }
}

// Kernel B: 128x128 tile per block; 4 waves in 2x2, each wave 64x64 output via
// 4x4 fragments of mfma_f32_16x16x32_bf16 with hi/lo 3-way split. Mask read
// once per element via nontemporal loads, software-pipelined in 8-element
// register batches (issue batch b+1, then dist+consume batch b); batch 0 is
// issued before the MFMA k-loop so its latency hides under the MFMAs.
__global__ __launch_bounds__(256, 3) void pair_kernel(
    const unsigned short* __restrict__ phi, const unsigned short* __restrict__ plo,
    const float* __restrict__ sq, const float* __restrict__ mask,
    float* __restrict__ ppos, float* __restrict__ pcnt) {
  __shared__ float cbuf[4][64][2];   // [wave][row-in-64][pos,cnt]

  const int bid = blockIdx.x;
  const int swz = (bid & 7) * 512 + (bid >> 3);  // XCD swizzle, bijective (4096%8==0)
  const int ib = swz >> 6, jb = swz & 63;
  const int i0 = ib * 128, j0 = jb * 128;

  const int t = threadIdx.x;
  const int wv = t >> 6, lane = t & 63;
  const int wi = wv >> 1, wj = wv & 1;
  const int lr = lane & 15, lk = lane >> 4;

  const int arow = i0 + wi * 64 + lr;  // + fi*16
  const int brow = j0 + wj * 64 + lr;  // + fj*16
  const int jcol = j0 + wj * 64 + lr;

  f32x4 acc[4][4];
#pragma unroll
  for (int a = 0; a < 4; ++a)
#pragma unroll
    for (int b = 0; b < 4; ++b) acc[a][b] = (f32x4){0.f, 0.f, 0.f, 0.f};

// issue 8 nontemporal mask loads for batch B (rows: fi*16 + lk*4 + rh*2 + {0,1})
#define ISSUE_B(BUF, B) do { \
  const int fi_ = (B) >> 1, rh_ = (B) & 1; \
  const int row0_ = i0 + wi * 64 + fi_ * 16 + lk * 4 + rh_ * 2; \
  const float* m0_ = mask + (size_t)row0_ * N + jcol; \
  const float* m1_ = m0_ + N; \
  _Pragma("unroll") for (int fj = 0; fj < 4; ++fj) { \
    BUF[fj]     = __builtin_nontemporal_load(m0_ + fj * 16); \
    BUF[4 + fj] = __builtin_nontemporal_load(m1_ + fj * 16); \
  } \
} while (0)

// compute 8 dists (pure VALU, no loads), then fold mask batch into pp/cc
#define PROC_B(BUF, B) do { \
  const int fi_ = (B) >> 1, rh_ = (B) & 1; \
  float d_[8]; \
  _Pragma("unroll") for (int rr = 0; rr < 2; ++rr) { \
    const int r_ = rh_ * 2 + rr; \
    const float sqi_ = sq[i0 + wi * 64 + fi_ * 16 + lk * 4 + r_]; \
    _Pragma("unroll") for (int fj = 0; fj < 4; ++fj) { \
      float g_ = acc[fi_][fj][r_]; \
      d_[rr * 4 + fj] = sqrtf(fmaxf(sqi_ + sqj[fj] - 2.0f * g_, 0.0f)); \
    } \
  } \
  _Pragma("unroll") for (int rr = 0; rr < 2; ++rr) { \
    const int r_ = rh_ * 2 + rr; \
    _Pragma("unroll") for (int fj = 0; fj < 4; ++fj) { \
      float m_ = BUF[rr * 4 + fj]; \
      pp[fi_][r_] = fmaf(d_[rr * 4 + fj], m_, pp[fi_][r_]); \
      cc[fi_][r_] += m_; \
    } \
  } \
} while (0)

  float mA[8], mB[8];
  ISSUE_B(mA, 0);   // in flight across the whole MFMA phase

#pragma unroll
  for (int kc = 0; kc < 4; ++kc) {
    const int kb = kc * 32 + lk * 8;
    bf16x8 ah[4], al[4], bh[4], bl[4];
#pragma unroll
    for (int f = 0; f < 4; ++f) {
      ah[f] = *(const bf16x8*)(phi + (size_t)(arow + f * 16) * D + kb);
      al[f] = *(const bf16x8*)(plo + (size_t)(arow + f * 16) * D + kb);
      bh[f] = *(const bf16x8*)(phi + (size_t)(brow + f * 16) * D + kb);
      bl[f] = *(const bf16x8*)(plo + (size_t)(brow + f * 16) * D + kb);
    }
#pragma unroll
    for (int fi = 0; fi < 4; ++fi)
#pragma unroll
      for (int fj = 0; fj < 4; ++fj) {
        acc[fi][fj] = __builtin_amdgcn_mfma_f32_16x16x32_bf16(ah[fi], bh[fj], acc[fi][fj], 0, 0, 0);
        acc[fi][fj] = __builtin_amdgcn_mfma_f32_16x16x32_bf16(ah[fi], bl[fj], acc[fi][fj], 0, 0, 0);
        acc[fi][fj] = __builtin_amdgcn_mfma_f32_16x16x32_bf16(al[fi], bh[fj], acc[fi][fj], 0, 0, 0);
      }
  }

  float sqj[4];
#pragma unroll
  for (int fj = 0; fj < 4; ++fj) sqj[fj] = sq[brow + fj * 16];

  float pp[4][4], cc[4][4];
#pragma unroll
  for (int a = 0; a < 4; ++a)
#pragma unroll
    for (int r = 0; r < 4; ++r) { pp[a][r] = 0.f; cc[a][r] = 0.f; }

  // software-pipelined mask stream: issue next batch, process current
  ISSUE_B(mB, 1); PROC_B(mA, 0);
  ISSUE_B(mA, 2); PROC_B(mB, 1);
  ISSUE_B(mB, 3); PROC_B(mA, 2);
  ISSUE_B(mA, 4); PROC_B(mB, 3);
  ISSUE_B(mB, 5); PROC_B(mA, 4);
  ISSUE_B(mA, 6); PROC_B(mB, 5);
  ISSUE_B(mB, 7); PROC_B(mA, 6);
  PROC_B(mB, 7);

#undef ISSUE_B
#undef PROC_B

  // reduce across the 16 lanes (lr) sharing each row
#pragma unroll
  for (int fi = 0; fi < 4; ++fi)
#pragma unroll
    for (int r = 0; r < 4; ++r) {
#pragma unroll
      for (int off = 1; off < 16; off <<= 1) {
        pp[fi][r] += __shfl_xor(pp[fi][r], off);
        cc[fi][r] += __shfl_xor(cc[fi][r], off);
      }
    }
  if (lr == 0) {
#pragma unroll
    for (int fi = 0; fi < 4; ++fi)
#pragma unroll
      for (int r = 0; r < 4; ++r) {
        cbuf[wv][fi * 16 + lk * 4 + r][0] = pp[fi][r];
        cbuf[wv][fi * 16 + lk * 4 + r][1] = cc[fi][r];
      }
  }
  __syncthreads();
  // coalesced per-slot writes: slot = jb*2 + wj, 64 contiguous rows per wave
  {
    const size_t slotbase = (size_t)(jb * 2 + wj) * N + i0 + wi * 64;
    ppos[slotbase + lane] = cbuf[wv][lane][0];
    pcnt[slotbase + lane] = cbuf[wv][lane][1];
  }
}

// Kernel C1: per-row totals over 128 slots -> (pos_avg - nd), block-sum in double.
__global__ __launch_bounds__(256) void reduce1(
    const float* __restrict__ ppos, const float* __restrict__ pcnt,
    const float* __restrict__ nd, double* __restrict__ bsum) {
  const int t = threadIdx.x;
  const int row = blockIdx.x * 256 + t;
  float ps = 0.f, cs = 0.f;
  for (int s = 0; s < 128; ++s) {
    ps += __builtin_nontemporal_load(ppos + (size_t)s * N + row);
    cs += __builtin_nontemporal_load(pcnt + (size_t)s * N + row);
  }
  double v = (double)(ps / fmaxf(cs, 1.0f)) - (double)nd[row];
  __shared__ double sd[256];
  sd[t] = v;
  __syncthreads();
  for (int s2 = 128; s2 > 0; s2 >>= 1) {
    if (t < s2) sd[t] += sd[t + s2];
    __syncthreads();
  }
  if (t == 0) bsum[blockIdx.x] = sd[0];
}

// Kernel C2: sum 32 block partials, divide by N.
__global__ void reduce2(const double* __restrict__ bsum, float* __restrict__ out) {
  int lane = threadIdx.x;
  double v = (lane < 32) ? bsum[lane] : 0.0;
#pragma unroll
  for (int off = 32; off; off >>= 1) v += __shfl_down(v, off);
  if (lane == 0) out[0] = (float)(v / (double)N);
}

extern "C" void kernel_launch(void* const* d_in, const int* in_sizes, int n_in,
                              void* d_out, int out_size, void* d_ws, size_t ws_size,
                              hipStream_t stream) {
  const float* pred = (const float*)d_in[0];
  const float* mask = (const float*)d_in[1];
  const float* neg  = (const float*)d_in[2];
  float* out = (float*)d_out;

  char* ws = (char*)d_ws;
  unsigned short* phi = (unsigned short*)ws;  ws += (size_t)N * D * 2;   // 2 MB
  unsigned short* plo = (unsigned short*)ws;  ws += (size_t)N * D * 2;   // 2 MB
  float* sq  = (float*)ws;                    ws += (size_t)N * 4;
  float* nd  = (float*)ws;                    ws += (size_t)N * 4;
  float* ppos = (float*)ws;                   ws += (size_t)128 * N * 4; // 4 MB
  float* pcnt = (float*)ws;                   ws += (size_t)128 * N * 4; // 4 MB
  double* bsum = (double*)ws;                 ws += 32 * 8;

  norm_kernel<<<N / 4, 256, 0, stream>>>(pred, neg, phi, plo, sq, nd);
  pair_kernel<<<(N / 128) * (N / 128), 256, 0, stream>>>(phi, plo, sq, mask, ppos, pcnt);
  reduce1<<<N / 256, 256, 0, stream>>>(ppos, pcnt, nd, bsum);
  reduce2<<<1, 64, 0, stream>>>(bsum, out);
}